// Round 10
// baseline (1115.268 us; speedup 1.0000x reference)
//
#include <hip/hip_runtime.h>
#include <hip/hip_bf16.h>

#define Bz 32
#define Tz 64
#define Sz 128
#define Hz 512
#define Vz 32000
#define G4 2048
#define NBLK 256
#define NPH 65

#define A_RLX __ATOMIC_RELAXED
#define SC_AG __HIP_MEMORY_SCOPE_AGENT

using bf16x8 = __attribute__((ext_vector_type(8))) short;
using f32x4  = __attribute__((ext_vector_type(4))) float;

__device__ __forceinline__ unsigned short f2bf(float f){
  unsigned int u = __float_as_uint(f);
  u += 0x7fffu + ((u >> 16) & 1u);
  return (unsigned short)(u >> 16);
}
__device__ __forceinline__ float sigf(float x){ return 1.f/(1.f + expf(-x)); }

__device__ __forceinline__ void stc(float* p, float v){
  __hip_atomic_store(p, v, A_RLX, SC_AG);
}
__device__ __forceinline__ float ldc(const float* p){
  return __hip_atomic_load(p, A_RLX, SC_AG);
}

// ---------------- grid barrier: FLAT 2-round-trip, single-writer/single-poller words ----
// arrive: bar[bid*4] (bid=1..255), polled by block0 thread tid=bid (coalesced lines)
// release: bar[1024 + bid*16], written by block0 thread bid, polled by block bid's t0
__device__ __forceinline__ void gbar(unsigned* bar, int bid, unsigned* ep){
  asm volatile("s_waitcnt vmcnt(0)" ::: "memory");   // drain this thread's stores
  __syncthreads();                                    // whole block drained
  const unsigned e = ++(*ep);
  const int tid = threadIdx.x;
  if (bid == 0){
    if (tid >= 1 && tid < 256){                       // parallel poll of all arrivals
      while (__hip_atomic_load(&bar[tid*4], A_RLX, SC_AG) != e)
        __builtin_amdgcn_s_sleep(1);
    }
    __syncthreads();
    if (tid < 256)                                    // fan-out release
      __hip_atomic_store(&bar[1024 + tid*16], e, A_RLX, SC_AG);
  } else {
    if (tid == 0){
      __hip_atomic_store(&bar[bid*4], e, A_RLX, SC_AG);
      while (__hip_atomic_load(&bar[1024 + bid*16], A_RLX, SC_AG) != e)
        __builtin_amdgcn_s_sleep(1);
    }
  }
  __syncthreads();
  __builtin_amdgcn_sched_barrier(0);
}

// ---------------- register transpose-reduce ----------------
__device__ __forceinline__ void xreduce(float (&a)[32], int lane){
  #pragma unroll
  for (int j = 0; j < 32; j++) a[j] += __shfl_xor(a[j], 32);
  #pragma unroll
  for (int st = 0; st < 5; st++){
    const int o = 16 >> st;
    bool hi = (lane & o) != 0;
    float tmp[16];
    #pragma unroll
    for (int j = 0; j < o; j++){
      float lo_v = a[j], hi_v = a[j + o];
      float sent = hi ? lo_v : hi_v;
      float recv = __shfl_xor(sent, o);
      tmp[j] = (hi ? hi_v : lo_v) + recv;
    }
    #pragma unroll
    for (int j = 0; j < o; j++) a[j] = tmp[j];
  }
}

// ---------------- dual LDS staging: ALL 64 coherent loads in flight ----------------
__device__ __forceinline__ void stage2c(float* dA, const float* sA,
                                        float* dB, const float* sB, int tid){
  float ra[32], rb[32];
  #pragma unroll
  for (int i = 0; i < 32; i++) ra[i] = ldc(sA + tid + i*512);
  #pragma unroll
  for (int i = 0; i < 32; i++) rb[i] = ldc(sB + tid + i*512);
  #pragma unroll
  for (int i = 0; i < 32; i++){
    int f = tid + i*512;
    dA[(f >> 9)*520 + (f & 511)] = ra[i];
  }
  #pragma unroll
  for (int i = 0; i < 32; i++){
    int f = tid + i*512;
    dB[(f >> 9)*520 + (f & 511)] = rb[i];
  }
}

// ---------------- init ----------------
__global__ __launch_bounds__(256) void init_state_v8(const float* __restrict__ h0,
    float* __restrict__ h0p, float* __restrict__ h1p, unsigned int* __restrict__ bar){
  int i = blockIdx.x*256 + threadIdx.x;   // grid 128 -> 32768
  if (i < 16384) h0p[16384 + i] = h0[i];            // h0(-1) -> slot 1
  else           h1p[3*16384 + (i - 16384)] = h0[i]; // h1(-1) -> slot 3
  if (i < 5120) bar[i] = 0u;
}

// ---------------- Wo -> bf16 ----------------
__global__ __launch_bounds__(256) void conv_bf16_kernel(const float* __restrict__ src,
    unsigned short* __restrict__ dst){
  int i = (blockIdx.x*256 + threadIdx.x)*4;
  float4 v = *(const float4*)(src + i);
  ushort4 o;
  o.x = f2bf(v.x); o.y = f2bf(v.y); o.z = f2bf(v.z); o.w = f2bf(v.w);
  *(ushort4*)(dst + i) = o;
}

// ---------------- weight packs: row-major, rows r = u*4+gate ----------------
__global__ __launch_bounds__(256) void pack_l0_v3(const float* __restrict__ W,
    float* __restrict__ out){
  int idx4 = blockIdx.x*256 + threadIdx.x;
  int r = idx4 >> 7, k4 = idx4 & 127;
  int srow = (r & 3)*Hz + (r >> 2);
  ((float4*)out)[idx4] = ((const float4*)W)[srow*128 + k4];
}
__global__ __launch_bounds__(256) void pack_l1_v3(const float* __restrict__ Wi,
    const float* __restrict__ Wh, float* __restrict__ out){
  int idx4 = blockIdx.x*256 + threadIdx.x;
  int r = idx4 >> 8, k4 = idx4 & 255;
  int srow = (r & 3)*Hz + (r >> 2);
  float4 v = (k4 < 128) ? ((const float4*)Wi)[srow*128 + k4]
                        : ((const float4*)Wh)[srow*128 + (k4 - 128)];
  ((float4*)out)[idx4] = v;
}

// ---------------- x0g: tiled fp32 GEMM, OUTPUT TRANSPOSED [t][col][b] ----------------
__global__ __launch_bounds__(256) void x0g_v3(const int* __restrict__ tgt,
    const float* __restrict__ emb, const float* __restrict__ W,
    const float* __restrict__ bi, const float* __restrict__ bh,
    float* __restrict__ out){
  __shared__ float As[32][68], Bs[32][68];
  __shared__ int tok_s[64];
  int tid = threadIdx.x;
  int m0 = blockIdx.y*64, n0 = blockIdx.x*64;
  if (tid < 64){ int tb = m0 + tid; tok_s[tid] = tgt[(tb & 31)*Tz + (tb >> 5)]; }
  __syncthreads();
  int lm = tid >> 2, lk = (tid & 3)*8;
  int ty = tid >> 4, tx = tid & 15;
  float acc[4][4] = {{0.f}};
  for (int kt = 0; kt < 16; kt++){
    float4 a0 = *(const float4*)(emb + (size_t)tok_s[lm]*Hz + kt*32 + lk);
    float4 a1 = *(const float4*)(emb + (size_t)tok_s[lm]*Hz + kt*32 + lk + 4);
    float4 b0 = *(const float4*)(W   + (size_t)(n0+lm)*Hz + kt*32 + lk);
    float4 b1 = *(const float4*)(W   + (size_t)(n0+lm)*Hz + kt*32 + lk + 4);
    __syncthreads();
    As[lk+0][lm]=a0.x; As[lk+1][lm]=a0.y; As[lk+2][lm]=a0.z; As[lk+3][lm]=a0.w;
    As[lk+4][lm]=a1.x; As[lk+5][lm]=a1.y; As[lk+6][lm]=a1.z; As[lk+7][lm]=a1.w;
    Bs[lk+0][lm]=b0.x; Bs[lk+1][lm]=b0.y; Bs[lk+2][lm]=b0.z; Bs[lk+3][lm]=b0.w;
    Bs[lk+4][lm]=b1.x; Bs[lk+5][lm]=b1.y; Bs[lk+6][lm]=b1.z; Bs[lk+7][lm]=b1.w;
    __syncthreads();
    #pragma unroll
    for (int k = 0; k < 32; k++){
      float4 av = *(const float4*)&As[k][ty*4];
      float4 bv = *(const float4*)&Bs[k][tx*4];
      acc[0][0]+=av.x*bv.x; acc[0][1]+=av.x*bv.y; acc[0][2]+=av.x*bv.z; acc[0][3]+=av.x*bv.w;
      acc[1][0]+=av.y*bv.x; acc[1][1]+=av.y*bv.y; acc[1][2]+=av.y*bv.z; acc[1][3]+=av.y*bv.w;
      acc[2][0]+=av.z*bv.x; acc[2][1]+=av.z*bv.y; acc[2][2]+=av.z*bv.z; acc[2][3]+=av.z*bv.w;
      acc[3][0]+=av.w*bv.x; acc[3][1]+=av.w*bv.y; acc[3][2]+=av.w*bv.z; acc[3][3]+=av.w*bv.w;
    }
  }
  #pragma unroll
  for (int j = 0; j < 4; j++){
    int col = n0 + tx*4 + j;
    float bias = bi[col] + bh[col];
    #pragma unroll
    for (int i = 0; i < 4; i++){
      int tb = m0 + ty*4 + i;
      int tt = tb >> 5, bb = tb & 31;
      out[((size_t)tt*2048 + col)*32 + bb] = acc[i][j] + bias;
    }
  }
}

// ---------------- persistent decoder v8: LSTM only, skewed, flat barrier ----------------
// phase tau (0..64): l0(tau) [tau<64] | l1(tau-1) [tau>=1]
__global__ __launch_bounds__(512, 1) void decoder_persist_v8(
    const float* __restrict__ Wp0, const float* __restrict__ Wp1,
    const float* x0gT,            // NO restrict: hist aliases into it
    const float* __restrict__ bi1, const float* __restrict__ bh1,
    const float* __restrict__ c0in,
    float* __restrict__ h0p,      // [2][16384]
    float* __restrict__ h1p,      // [4][16384]
    float* hist,                  // = x0g base (front 16384 of slot t)
    float* __restrict__ cbuf,     // [2][16384] final c out
    unsigned* __restrict__ bar){
  extern __shared__ float sm[];
  float* hstA = sm;              // [32][520] 16640
  float* hstB = sm + 16640;      // [32][520] 16640
  float* gsA  = sm + 33280;      // 512
  float* gsB  = sm + 33792;      // 512
  float4* hA4 = (float4*)hstA;
  float4* hB4 = (float4*)hstB;

  const int bid = blockIdx.x, tid = threadIdx.x;
  const int w4 = tid >> 6, lane = tid & 63;
  const int kh = w4 >> 2, rpair = w4 & 3;
  const int r0 = bid*8 + rpair*2, r1 = r0 + 1;
  unsigned ep = 0;

  // ---- persistent weights -> VGPRs ----
  const float4* Wp0_4 = (const float4*)Wp0;
  const float4* Wp1_4 = (const float4*)Wp1;
  float4 w0A  = Wp0_4[r0*128 + kh*64 + lane];
  float4 w0B  = Wp0_4[r1*128 + kh*64 + lane];
  float4 w1xA = Wp1_4[r0*256 +       kh*64 + lane];
  float4 w1xB = Wp1_4[r1*256 +       kh*64 + lane];
  float4 w1hA = Wp1_4[r0*256 + 128 + kh*64 + lane];
  float4 w1hB = Wp1_4[r1*256 + 128 + kh*64 + lane];
  float bs_i=0.f, bs_f=0.f, bs_g=0.f, bs_o=0.f;
  float c0_reg=0.f, c1_reg=0.f;
  if (tid < 64){
    int b = tid & 31, u = bid*2 + (tid >> 5);
    bs_i = bi1[u]        + bh1[u];
    bs_f = bi1[512+u]    + bh1[512+u];
    bs_g = bi1[1024+u]   + bh1[1024+u];
    bs_o = bi1[1536+u]   + bh1[1536+u];
    c0_reg = c0in[b*512 + u];
    c1_reg = c0in[16384 + b*512 + u];
  }
  __syncthreads();

  for (int tau = 0; tau < NPH; ++tau){
    // ---- stage h0(tau-1)->hstA, h1(tau-2)->hstB (coherent loads) ----
    stage2c(hstA, h0p + ((tau+1)&1)*16384, hstB, h1p + ((tau+2)&3)*16384, tid);
    // ---- x0gT(tau) prefetch: coalesced over b ----
    float xgi=0.f, xgf=0.f, xgg=0.f, xgo=0.f;
    if (tau < 64 && tid < 64){
      int b = tid & 31, u = bid*2 + (tid >> 5);
      const float* xg = x0gT + (size_t)tau*65536;
      xgi = xg[(u       )*32 + b];
      xgf = xg[(512  + u)*32 + b];
      xgg = xg[(1024 + u)*32 + b];
      xgo = xg[(1536 + u)*32 + b];
    }
    __syncthreads();
    // ---- combined gemv: l0(tau) rows + l1(tau-1) rows ----
    {
      float aL0A[32], aL0B[32], aL1A[32], aL1B[32];
      #pragma unroll
      for (int b = 0; b < 32; b++){ aL0A[b]=0.f; aL0B[b]=0.f; aL1A[b]=0.f; aL1B[b]=0.f; }
      const float4* pA = hA4 + kh*64 + lane;
      const float4* pB = hB4 + kh*64 + lane;
      #pragma unroll
      for (int b = 0; b < 32; b++){
        float4 ha = pA[b*130];
        float4 hb = pB[b*130];
        aL0A[b] = fmaf(ha.x,w0A.x, fmaf(ha.y,w0A.y, fmaf(ha.z,w0A.z, fmaf(ha.w,w0A.w, aL0A[b]))));
        aL0B[b] = fmaf(ha.x,w0B.x, fmaf(ha.y,w0B.y, fmaf(ha.z,w0B.z, fmaf(ha.w,w0B.w, aL0B[b]))));
        float t1 = fmaf(ha.x,w1xA.x, fmaf(ha.y,w1xA.y, fmaf(ha.z,w1xA.z, fmaf(ha.w,w1xA.w, aL1A[b]))));
        aL1A[b] = fmaf(hb.x,w1hA.x, fmaf(hb.y,w1hA.y, fmaf(hb.z,w1hA.z, fmaf(hb.w,w1hA.w, t1))));
        float t2 = fmaf(ha.x,w1xB.x, fmaf(ha.y,w1xB.y, fmaf(ha.z,w1xB.z, fmaf(ha.w,w1xB.w, aL1B[b]))));
        aL1B[b] = fmaf(hb.x,w1hB.x, fmaf(hb.y,w1hB.y, fmaf(hb.z,w1hB.z, fmaf(hb.w,w1hB.w, t2))));
      }
      xreduce(aL0A, lane); xreduce(aL0B, lane);
      gsA[kh*256 + (rpair*2 + (lane >= 32 ? 1 : 0))*32 + (lane & 31)] = (lane < 32) ? aL0A[0] : aL0B[0];
      xreduce(aL1A, lane); xreduce(aL1B, lane);
      gsB[kh*256 + (rpair*2 + (lane >= 32 ? 1 : 0))*32 + (lane & 31)] = (lane < 32) ? aL1A[0] : aL1B[0];
    }
    __syncthreads();
    // ---- cells (tid<64) ----
    if (tid < 64){
      int ul = tid >> 5, b = tid & 31, u = bid*2 + ul, rl = ul*4;
      if (tau < 64){
        float gi = gsA[(rl+0)*32+b] + gsA[256+(rl+0)*32+b] + xgi;
        float gf = gsA[(rl+1)*32+b] + gsA[256+(rl+1)*32+b] + xgf;
        float gg = gsA[(rl+2)*32+b] + gsA[256+(rl+2)*32+b] + xgg;
        float go = gsA[(rl+3)*32+b] + gsA[256+(rl+3)*32+b] + xgo;
        float cn = sigf(gf)*c0_reg + sigf(gi)*tanhf(gg);
        c0_reg = cn;
        stc(h0p + (tau&1)*16384 + b*512 + u, sigf(go)*tanhf(cn));
      }
      if (tau >= 1){
        int t1s = tau - 1;
        float gi = gsB[(rl+0)*32+b] + gsB[256+(rl+0)*32+b] + bs_i;
        float gf = gsB[(rl+1)*32+b] + gsB[256+(rl+1)*32+b] + bs_f;
        float gg = gsB[(rl+2)*32+b] + gsB[256+(rl+2)*32+b] + bs_g;
        float go = gsB[(rl+3)*32+b] + gsB[256+(rl+3)*32+b] + bs_o;
        float cn = sigf(gf)*c1_reg + sigf(gi)*tanhf(gg);
        c1_reg = cn;
        float hv = sigf(go)*tanhf(cn);
        stc(h1p + (t1s&3)*16384 + b*512 + u, hv);
        hist[(size_t)t1s*65536 + b*512 + u] = hv;   // plain; read after kernel end
      }
    }
    gbar(bar, bid, &ep);
  }
  // ---- final c writeback ----
  if (tid < 64){
    int b = tid & 31, u = bid*2 + (tid >> 5);
    cbuf[b*512 + u] = c0_reg;
    cbuf[16384 + b*512 + u] = c1_reg;
  }
}

// ---------------- batched attention: scores+softmax+ctx per (t,b) ----------------
__global__ __launch_bounds__(256) void attn_batch(const float* hist,
    const float* __restrict__ enc, float* ctxout){
  __shared__ float h_s[Hz], e_s[Sz], red_s[2];
  const int bid = blockIdx.x;             // 2048: t*32 + b
  const int t = bid >> 5, b = bid & 31, tid = threadIdx.x;
  const float* h1 = hist + (size_t)t*65536 + b*512;
  *(float2*)(h_s + tid*2) = *(const float2*)(h1 + tid*2);
  __syncthreads();
  {
    int s = tid >> 1, half = tid & 1;
    const float4* e4 = (const float4*)(enc + ((size_t)b*Sz + s)*Hz + half*256);
    const float4* h4 = (const float4*)(h_s + half*256);
    float a = 0.f;
    #pragma unroll 16
    for (int k = 0; k < 64; k++){
      float4 e = e4[k], h = h4[k];
      a += e.x*h.x + e.y*h.y + e.z*h.z + e.w*h.w;
    }
    a += __shfl_xor(a, 1);
    if (!half) e_s[s] = a;
  }
  __syncthreads();
  if (tid < 64){
    float v = fmaxf(e_s[tid], e_s[tid+64]);
    #pragma unroll
    for (int o = 32; o; o >>= 1) v = fmaxf(v, __shfl_xor(v, o));
    if (tid == 0) red_s[0] = v;
  }
  __syncthreads();
  if (tid < Sz) e_s[tid] = expf(e_s[tid] - red_s[0]);
  __syncthreads();
  if (tid < 64){
    float v = e_s[tid] + e_s[tid+64];
    #pragma unroll
    for (int o = 32; o; o >>= 1) v += __shfl_xor(v, o);
    if (tid == 0) red_s[1] = v;
  }
  __syncthreads();
  {
    float inv = 1.f/red_s[1];
    int k0 = tid*2;
    float c0 = 0.f, c1 = 0.f;
    const float* ep = enc + (size_t)b*Sz*Hz + k0;
    #pragma unroll 8
    for (int s = 0; s < Sz; s++){
      float2 ev = *(const float2*)(ep + (size_t)s*Hz);
      float pr = e_s[s];
      c0 += pr*ev.x; c1 += pr*ev.y;
    }
    float2 o; o.x = c0*inv; o.y = c1*inv;
    *(float2*)(ctxout + (size_t)t*65536 + 32768 + b*512 + k0) = o;
  }
}

// ---------------- out_att GEMM: [2048 x 512] = [hist|ctx][2048x1024] @ Wc^T, tanh, ->bf16 ----
__global__ __launch_bounds__(256) void outatt_gemm(const float* xg,
    const float* __restrict__ Wc, const float* __restrict__ bc,
    unsigned short* __restrict__ oa){
  __shared__ float As[32][68], Bs[32][68];
  int tid = threadIdx.x;
  int m0 = blockIdx.y*64, n0 = blockIdx.x*64;
  int lm = tid >> 2, lk = (tid & 3)*8;
  int ty = tid >> 4, tx = tid & 15;
  int am = m0 + lm, at = am >> 5, ab = am & 31;
  const float* arow = xg + (size_t)at*65536 + ab*512;
  float acc[4][4] = {{0.f}};
  for (int kt = 0; kt < 32; kt++){
    int k = kt*32 + lk;
    const float* asrc = (k < 512) ? (arow + k) : (arow + 32768 + (k - 512));
    float4 a0 = *(const float4*)asrc;
    float4 a1 = *(const float4*)(asrc + 4);
    float4 b0 = *(const float4*)(Wc + (size_t)(n0+lm)*1024 + k);
    float4 b1 = *(const float4*)(Wc + (size_t)(n0+lm)*1024 + k + 4);
    __syncthreads();
    As[lk+0][lm]=a0.x; As[lk+1][lm]=a0.y; As[lk+2][lm]=a0.z; As[lk+3][lm]=a0.w;
    As[lk+4][lm]=a1.x; As[lk+5][lm]=a1.y; As[lk+6][lm]=a1.z; As[lk+7][lm]=a1.w;
    Bs[lk+0][lm]=b0.x; Bs[lk+1][lm]=b0.y; Bs[lk+2][lm]=b0.z; Bs[lk+3][lm]=b0.w;
    Bs[lk+4][lm]=b1.x; Bs[lk+5][lm]=b1.y; Bs[lk+6][lm]=b1.z; Bs[lk+7][lm]=b1.w;
    __syncthreads();
    #pragma unroll
    for (int k2 = 0; k2 < 32; k2++){
      float4 av = *(const float4*)&As[k2][ty*4];
      float4 bv = *(const float4*)&Bs[k2][tx*4];
      acc[0][0]+=av.x*bv.x; acc[0][1]+=av.x*bv.y; acc[0][2]+=av.x*bv.z; acc[0][3]+=av.x*bv.w;
      acc[1][0]+=av.y*bv.x; acc[1][1]+=av.y*bv.y; acc[1][2]+=av.y*bv.z; acc[1][3]+=av.y*bv.w;
      acc[2][0]+=av.z*bv.x; acc[2][1]+=av.z*bv.y; acc[2][2]+=av.z*bv.z; acc[2][3]+=av.z*bv.w;
      acc[3][0]+=av.w*bv.x; acc[3][1]+=av.w*bv.y; acc[3][2]+=av.w*bv.z; acc[3][3]+=av.w*bv.w;
    }
  }
  #pragma unroll
  for (int j = 0; j < 4; j++){
    int col = n0 + tx*4 + j;
    float bias = bc[col];
    #pragma unroll
    for (int i = 0; i < 4; i++){
      int m = m0 + ty*4 + i;
      int t = m >> 5, b = m & 31;
      oa[((size_t)(b*64 + t))*512 + col] = f2bf(tanhf(acc[i][j] + bias));
    }
  }
}

// ---------------- pred GEMM: XCD-pinned + swizzled LDS ----------------
__global__ __launch_bounds__(256) void pred_gemm_v2(const unsigned short* __restrict__ A,
    const unsigned short* __restrict__ Bm, const float* __restrict__ bo,
    float* __restrict__ out){
  __shared__ unsigned short As[128*32];
  __shared__ unsigned short Bs[128*32];
  int bid = blockIdx.x;
  int xcd = bid & 7, lin = bid >> 3;
  int ntile = xcd*32 + (lin & 31);
  int mtile = lin >> 5;
  if (ntile >= 250) return;
  int n0 = ntile*128, m0 = mtile*128;
  int tid = threadIdx.x, lane = tid & 63, wid = tid >> 6;
  f32x4 acc[4][4];
  #pragma unroll
  for (int i = 0; i < 4; i++)
    #pragma unroll
    for (int j = 0; j < 4; j++)
      #pragma unroll
      for (int r = 0; r < 4; r++) acc[i][j][r] = 0.f;

  int wm = wid >> 1, wn = wid & 1;
  int r16 = lane & 15, kgr = lane >> 4;

  for (int kt = 0; kt < Hz/32; kt++){
    __syncthreads();
    #pragma unroll
    for (int call = 0; call < 2; call++){
      int c = call*256 + tid;
      int row = c >> 2, kg = c & 3;
      int kgs = kg ^ ((row >> 1) & 3);
      *(int4*)&As[row*32 + kgs*8] = *(const int4*)(A  + (size_t)(m0+row)*Hz + kt*32 + kg*8);
      *(int4*)&Bs[row*32 + kgs*8] = *(const int4*)(Bm + (size_t)(n0+row)*Hz + kt*32 + kg*8);
    }
    __syncthreads();
    bf16x8 aF[4], bF[4];
    #pragma unroll
    for (int i = 0; i < 4; i++){
      int ra = wm*64 + i*16 + r16;
      int rb = wn*64 + i*16 + r16;
      aF[i] = *(const bf16x8*)&As[ra*32 + (kgr ^ ((ra>>1)&3))*8];
      bF[i] = *(const bf16x8*)&Bs[rb*32 + (kgr ^ ((rb>>1)&3))*8];
    }
    #pragma unroll
    for (int i = 0; i < 4; i++)
      #pragma unroll
      for (int j = 0; j < 4; j++)
        acc[i][j] = __builtin_amdgcn_mfma_f32_16x16x32_bf16(aF[i], bF[j], acc[i][j], 0, 0, 0);
  }

  int rg = lane >> 4;
  #pragma unroll
  for (int i = 0; i < 4; i++)
    #pragma unroll
    for (int j = 0; j < 4; j++){
      int col = n0 + wn*64 + j*16 + r16;
      float bias = bo[col];
      #pragma unroll
      for (int r = 0; r < 4; r++){
        int row = m0 + wm*64 + i*16 + rg*4 + r;   // row = b*64 + t
        out[(size_t)row*Vz + col] = acc[i][j][r] + bias;
      }
    }
}

// ---------------- final h,c copy ----------------
__global__ __launch_bounds__(256) void copy_hc_v4(const float* __restrict__ h0fin,
    const float* __restrict__ h1fin, const float* __restrict__ cbuf,
    float* __restrict__ out_hc){
  int i = blockIdx.x*256 + threadIdx.x;
  float v;
  if (i < 16384)      v = h0fin[i];
  else if (i < 32768) v = h1fin[i-16384];
  else                v = cbuf[i-32768];
  out_hc[i] = v;
}

extern "C" void kernel_launch(void* const* d_in, const int* in_sizes, int n_in,
                              void* d_out, int out_size, void* d_ws, size_t ws_size,
                              hipStream_t stream){
  const int*   tgt = (const int*)  d_in[0];
  const float* h0  = (const float*)d_in[1];
  const float* c0  = (const float*)d_in[2];
  const float* enc = (const float*)d_in[3];
  const float* emb = (const float*)d_in[4];
  const float* Wih = (const float*)d_in[5];
  const float* Whh = (const float*)d_in[6];
  const float* bih = (const float*)d_in[7];
  const float* bhh = (const float*)d_in[8];
  const float* Wc  = (const float*)d_in[9];
  const float* bc  = (const float*)d_in[10];
  const float* Wo  = (const float*)d_in[11];
  const float* bo  = (const float*)d_in[12];
  float* out = (float*)d_out;

  // workspace layout (floats)
  // x0g slot t (65536 f): [0:16384) hist(t) after phase t | [32768:49152) ctx(t)
  float* x0g  = (float*)d_ws;                 // 4,194,304
  float* h0p  = x0g  + 4194304;               // 32,768  [2][16384]
  float* h1p  = h0p  + 32768;                 // 65,536  [4][16384]
  float* cbuf = h1p  + 65536;                 // 32,768
  float* Wp0  = cbuf + 32768;                 // 1,048,576
  float* Wp1  = Wp0  + 1048576;               // 2,097,152
  unsigned int* bar = (unsigned int*)(Wp1 + 2097152);           // 5120 words
  unsigned short* oa    = (unsigned short*)(bar + 5120);        // 1,048,576 us [b][t][u]
  unsigned short* wo_bf = oa + 1048576;       // 16,384,000 us (32MB)

  const int DLDS_BYTES = 34304 * 4;           // 137.2 KB dynamic LDS
  hipFuncSetAttribute((const void*)decoder_persist_v8,
      hipFuncAttributeMaxDynamicSharedMemorySize, DLDS_BYTES);

  init_state_v8<<<128, 256, 0, stream>>>(h0, h0p, h1p, bar);
  conv_bf16_kernel<<<16000, 256, 0, stream>>>(Wo, wo_bf);
  pack_l0_v3<<<1024, 256, 0, stream>>>(Whh, Wp0);
  pack_l1_v3<<<2048, 256, 0, stream>>>(Wih + (size_t)G4*Hz, Whh + (size_t)G4*Hz, Wp1);
  x0g_v3<<<dim3(32, 32), 256, 0, stream>>>(tgt, emb, Wih, bih, bhh, x0g);

  decoder_persist_v8<<<NBLK, 512, DLDS_BYTES, stream>>>(
      Wp0, Wp1, x0g, bih + G4, bhh + G4, c0,
      h0p, h1p, /*hist=*/x0g, cbuf, (unsigned int*)bar);

  attn_batch<<<2048, 256, 0, stream>>>(x0g, enc, x0g);
  outatt_gemm<<<dim3(8, 32), 256, 0, stream>>>(x0g, Wc, bc, oa);
  pred_gemm_v2<<<4096, 256, 0, stream>>>(oa, wo_bf, bo, out);
  copy_hc_v4<<<256, 256, 0, stream>>>(h0p + 16384, x0g + (size_t)63*65536, cbuf,
                                      out + (size_t)Bz*Tz*Vz);

  (void)in_sizes; (void)n_in; (void)out_size; (void)ws_size;
}